// Round 8
// baseline (23.471 us; speedup 1.0000x reference)
//
#include <hip/hip_runtime.h>
#include <hip/hip_bf16.h>

typedef float  f32x4  __attribute__((ext_vector_type(4)));
typedef short  bf16x8 __attribute__((ext_vector_type(8)));
typedef short  s16x4  __attribute__((ext_vector_type(4)));

#define NB   64
#define NL1  512
#define NL2  32
#define ND   600
// panel: per batch 19 steps x [half][g][r16] x 8 shorts = 19456 shorts (38 KB)
#define PBATCH 19456
#define PANEL_SH ((size_t)NB * PBATCH)          // 1245184 shorts
#define W1P_OFF  PANEL_SH                        // 608 shorts
#define AT4_OFF  (PANEL_SH + 608)                // float region after (4B aligned)

static __device__ __forceinline__ short f2bf(float f) {
    __hip_bfloat16 h = __float2bfloat16(f);
    return __builtin_bit_cast(short, h);
}

// Phase 1: build bf16(asp*w3) panel in MFMA B-fragment order, w1 fragments,
// and asp.w2 partial sums. Grid (64 batches, 4 K-quarters), 256 thr.
__global__ __launch_bounds__(256, 4)
void prep_kernel(const float* __restrict__ asp,
                 const float* __restrict__ wu,
                 short* __restrict__ ws_sh)
{
    short* panel = ws_sh;
    short* w1p   = ws_sh + W1P_OFF;
    float* at4   = (float*)(ws_sh + AT4_OFF);

    const int b    = blockIdx.x;
    const int q    = blockIdx.y;            // K-quarter
    const int sbeg = q * 5;
    const int send = (q == 3) ? 19 : sbeg + 5;
    const int tid  = threadIdx.x;
    const int j    = tid >> 3;              // asp row 0..31
    const int sub  = tid & 7;
    const int gq   = sub >> 1;              // k-subgroup
    const int e4   = (sub & 1) * 4;
    const int half = j >> 4;
    const int r    = j & 15;

    const float* arow = asp + ((size_t)b * NL2 + j) * ND;
    short* pb = panel + (size_t)b * PBATCH;

    float at = 0.f;
    #pragma unroll
    for (int s = sbeg; s < send; ++s) {
        const int k = s * 32 + sub * 4;
        if (k < ND) {
            const float4 v  = *(const float4*)(arow + k);
            const float4 w2 = *(const float4*)(wu + ND + k);
            const float4 w3 = *(const float4*)(wu + 2 * ND + k);
            at += v.x * w2.x + v.y * w2.y + v.z * w2.z + v.w * w2.w;
            s16x4 h;
            h.x = f2bf(v.x * w3.x);
            h.y = f2bf(v.y * w3.y);
            h.z = f2bf(v.z * w3.z);
            h.w = f2bf(v.w * w3.w);
            *(s16x4*)&pb[(((s * 2 + half) * 4 + gq) * 16 + r) * 8 + e4] = h;
        }
    }
    at += __shfl_xor(at, 1);
    at += __shfl_xor(at, 2);
    at += __shfl_xor(at, 4);
    if (sub == 0) at4[((size_t)b * 4 + q) * NL2 + j] = at;

    if (q == 3) {
        // zero panel tail fragments (s=18, g=3 -> k=600..607)
        if (tid < 32) {
            const int hh = tid >> 4, rr = tid & 15;
            #pragma unroll
            for (int e = 0; e < 8; ++e)
                pb[(((18 * 2 + hh) * 4 + 3) * 16 + rr) * 8 + e] = 0;
        }
        // w1 fragments (shared): block b==0 writes
        if (b == 0 && tid < 76) {
            const int s = tid >> 2, gg = tid & 3;
            #pragma unroll
            for (int e = 0; e < 8; ++e) {
                const int k = s * 32 + gg * 8 + e;
                w1p[(s * 4 + gg) * 8 + e] = (k < ND) ? f2bf(wu[k]) : (short)0;
            }
        }
    }
}

// Phase 2: zero-LDS, zero-barrier consumer. 4 independent waves per block,
// wave = 16 ctx rows x 32 cols. B-fragments are contiguous L2-hit loads.
__global__ __launch_bounds__(256, 2)
void align_kernel(const float* __restrict__ ctx,
                  const short* __restrict__ ws_sh,
                  float* __restrict__ out)
{
    const short* panel = ws_sh;
    const short* w1p   = ws_sh + W1P_OFF;
    const float* at4   = (const float*)(ws_sh + AT4_OFF);

    const int tid     = threadIdx.x;
    const int lane    = tid & 63;
    const int wid     = tid >> 6;
    const int b       = blockIdx.x;          // id%8 = b%8 -> batch-affine XCD
    const int rowbase = blockIdx.y * 64 + wid * 16;

    const int r16 = lane & 15;               // A row / D col
    const int g   = lane >> 4;               // k-subgroup

    const float* actx = ctx + ((size_t)b * NL1 + rowbase + r16) * ND + 8 * g;
    const short* pb   = panel + (size_t)b * PBATCH;
    // B-frag: lane offset = lane*8 shorts (16 B/lane contiguous, 1 KB/instr)

#define ISSUE_C(t, C0, C1)                                                     \
    if ((t) <= 17 || ((t) == 18 && g < 3)) {                                   \
        C0 = *(const float4*)(actx + (t) * 32);                                \
        C1 = *(const float4*)(actx + (t) * 32 + 4);                            \
    } else if ((t) == 18) {                                                    \
        C0 = make_float4(0.f, 0.f, 0.f, 0.f);                                  \
        C1 = make_float4(0.f, 0.f, 0.f, 0.f);                                  \
    }

#define ISSUE_B(t, F0, F1, WF)                                                 \
    if ((t) <= 18) {                                                           \
        F0 = *(const bf16x8*)&pb[(t) * 1024 + lane * 8];                       \
        F1 = *(const bf16x8*)&pb[(t) * 1024 + 512 + lane * 8];                 \
        WF = *(const bf16x8*)&w1p[((t) * 4 + g) * 8];                          \
    }

    float4 cA0, cA1, cB0, cB1;
    bf16x8 fA0, fA1, wA, fB0, fB1, wB;
    ISSUE_C(0, cA0, cA1) ISSUE_B(0, fA0, fA1, wA)
    ISSUE_C(1, cB0, cB1) ISSUE_B(1, fB0, fB1, wB)

    f32x4 acc0 = {0,0,0,0};   // cross, cols 0..15
    f32x4 acc1 = {0,0,0,0};   // cross, cols 16..31
    f32x4 acc2 = {0,0,0,0};   // ctx.w1 (B = w1 broadcast)

#define STEP(s, C0, C1, F0, F1, WF)                                            \
    {                                                                          \
        bf16x8 af;                                                             \
        af[0] = f2bf(C0.x); af[1] = f2bf(C0.y);                                \
        af[2] = f2bf(C0.z); af[3] = f2bf(C0.w);                                \
        af[4] = f2bf(C1.x); af[5] = f2bf(C1.y);                                \
        af[6] = f2bf(C1.z); af[7] = f2bf(C1.w);                                \
        acc0 = __builtin_amdgcn_mfma_f32_16x16x32_bf16(af, F0, acc0, 0, 0, 0); \
        acc1 = __builtin_amdgcn_mfma_f32_16x16x32_bf16(af, F1, acc1, 0, 0, 0); \
        acc2 = __builtin_amdgcn_mfma_f32_16x16x32_bf16(af, WF, acc2, 0, 0, 0); \
        ISSUE_C((s) + 2, C0, C1)                                               \
        ISSUE_B((s) + 2, F0, F1, WF)                                           \
    }

    #pragma unroll 1
    for (int s = 0; s < 18; s += 2) {
        STEP(s,     cA0, cA1, fA0, fA1, wA)
        STEP(s + 1, cB0, cB1, fB0, fB1, wB)
    }
    STEP(18, cA0, cA1, fA0, fA1, wA)       // prefetch t=20 guarded out

#undef STEP
#undef ISSUE_B
#undef ISSUE_C

    // ---- epilogue: D row = g*4 + reg, D col = r16 ----
    float atj0 = 0.f, atj1 = 0.f;
    #pragma unroll
    for (int q = 0; q < 4; ++q) {
        atj0 += at4[((size_t)b * 4 + q) * NL2 + r16];
        atj1 += at4[((size_t)b * 4 + q) * NL2 + 16 + r16];
    }
    float* orow = out + ((size_t)b * NL1 + rowbase + g * 4) * NL2;
    #pragma unroll
    for (int r = 0; r < 4; ++r) {
        const float cterm = acc2[r];
        orow[r * NL2 + r16]      = acc0[r] + cterm + atj0;
        orow[r * NL2 + 16 + r16] = acc1[r] + cterm + atj1;
    }
}

extern "C" void kernel_launch(void* const* d_in, const int* in_sizes, int n_in,
                              void* d_out, int out_size, void* d_ws, size_t ws_size,
                              hipStream_t stream) {
    (void)in_sizes; (void)n_in; (void)ws_size; (void)out_size;
    // d_in: [0]=batch_size(int scalar), [1]=ctx f32, [2]=asp f32, [3]=w_u f32
    const float* ctx = (const float*)d_in[1];
    const float* asp = (const float*)d_in[2];
    const float* wu  = (const float*)d_in[3];
    float* out = (float*)d_out;
    short* ws_sh = (short*)d_ws;

    dim3 g1(NB, 4);
    prep_kernel<<<g1, 256, 0, stream>>>(asp, wu, ws_sh);
    dim3 g2(NB, NL1 / 64);
    align_kernel<<<g2, 256, 0, stream>>>(ctx, ws_sh, out);
}